// Round 1
// baseline (2621.925 us; speedup 1.0000x reference)
//
#include <hip/hip_runtime.h>
#include <cstddef>
#include <cstdint>

// Tiled f32 GEMM, 64x64 tile, K-tile 16, 4x4 per thread, register-prefetch.
// ACT: 0 = none, 1 = tanh, 2 = sigmoid
#define TK 16
#define TM 64
#define TN 64

template <int ACT>
__global__ __launch_bounds__(256)
void gemm_nn_f32(const float* __restrict__ A, const float* __restrict__ B,
                 float* __restrict__ C, int M, int N, int K) {
  __shared__ float As[TK][TM + 4];  // [kk][m], row stride 68 floats (16B aligned)
  __shared__ float Bs[TK][TN + 4];  // [kk][n]
  const int tid = threadIdx.x;
  const int tx = tid & 15;
  const int ty = tid >> 4;
  const int row0 = blockIdx.y * TM;
  const int col0 = blockIdx.x * TN;

  // staging assignment: one float4 per thread for A and for B
  const int a_m = tid >> 2;          // 0..63
  const int a_k = (tid & 3) << 2;    // 0,4,8,12
  const int b_k = tid >> 4;          // 0..15
  const int b_n = (tid & 15) << 2;   // 0..60

  float acc[4][4] = {};
  const int ntile = (K + TK - 1) / TK;

  auto ld_a = [&](int k0) {
    float4 v = make_float4(0.f, 0.f, 0.f, 0.f);
    int r = row0 + a_m, k = k0 + a_k;
    if (r < M && k + 3 < K) v = *(const float4*)(A + (size_t)r * K + k);
    return v;
  };
  auto ld_b = [&](int k0) {
    float4 v = make_float4(0.f, 0.f, 0.f, 0.f);
    int k = k0 + b_k, c = col0 + b_n;
    if (k < K && c + 3 < N) v = *(const float4*)(B + (size_t)k * N + c);
    return v;
  };

  float4 pa = ld_a(0), pb = ld_b(0);

  for (int t = 0; t < ntile; ++t) {
    __syncthreads();
    As[a_k + 0][a_m] = pa.x;
    As[a_k + 1][a_m] = pa.y;
    As[a_k + 2][a_m] = pa.z;
    As[a_k + 3][a_m] = pa.w;
    *(float4*)&Bs[b_k][b_n] = pb;
    __syncthreads();
    if (t + 1 < ntile) { pa = ld_a((t + 1) * TK); pb = ld_b((t + 1) * TK); }
#pragma unroll
    for (int kk = 0; kk < TK; ++kk) {
      float4 a = *(const float4*)&As[kk][ty << 2];
      float4 b = *(const float4*)&Bs[kk][tx << 2];
      float av[4] = {a.x, a.y, a.z, a.w};
      float bv[4] = {b.x, b.y, b.z, b.w};
#pragma unroll
      for (int i = 0; i < 4; ++i)
#pragma unroll
        for (int j = 0; j < 4; ++j) acc[i][j] += av[i] * bv[j];
    }
  }

#pragma unroll
  for (int i = 0; i < 4; ++i) {
    int r = row0 + (ty << 2) + i;
    if (r >= M) continue;
#pragma unroll
    for (int j = 0; j < 4; ++j) {
      int c = col0 + (tx << 2) + j;
      if (c >= N) continue;
      float v = acc[i][j];
      if (ACT == 1) v = tanhf(v);
      if (ACT == 2) v = 1.0f / (1.0f + __expf(-v));
      C[(size_t)r * N + c] = v;
    }
  }
}

// C[M,N] = act(A[M,K] @ B[N,K]^T)
template <int ACT>
__global__ __launch_bounds__(256)
void gemm_nt_f32(const float* __restrict__ A, const float* __restrict__ B,
                 float* __restrict__ C, int M, int N, int K) {
  __shared__ float As[TK][TM + 4];
  __shared__ float Bs[TK][TN + 4];
  const int tid = threadIdx.x;
  const int tx = tid & 15;
  const int ty = tid >> 4;
  const int row0 = blockIdx.y * TM;
  const int col0 = blockIdx.x * TN;

  const int a_m = tid >> 2;
  const int a_k = (tid & 3) << 2;
  const int b_n = tid >> 2;          // 0..63 (row of B)
  const int b_k = (tid & 3) << 2;    // 0,4,8,12

  float acc[4][4] = {};
  const int ntile = (K + TK - 1) / TK;

  auto ld_a = [&](int k0) {
    float4 v = make_float4(0.f, 0.f, 0.f, 0.f);
    int r = row0 + a_m, k = k0 + a_k;
    if (r < M && k + 3 < K) v = *(const float4*)(A + (size_t)r * K + k);
    return v;
  };
  auto ld_b = [&](int k0) {
    float4 v = make_float4(0.f, 0.f, 0.f, 0.f);
    int c = col0 + b_n, k = k0 + b_k;
    if (c < N && k + 3 < K) v = *(const float4*)(B + (size_t)c * K + k);
    return v;
  };

  float4 pa = ld_a(0), pb = ld_b(0);

  for (int t = 0; t < ntile; ++t) {
    __syncthreads();
    As[a_k + 0][a_m] = pa.x;
    As[a_k + 1][a_m] = pa.y;
    As[a_k + 2][a_m] = pa.z;
    As[a_k + 3][a_m] = pa.w;
    Bs[b_k + 0][b_n] = pb.x;
    Bs[b_k + 1][b_n] = pb.y;
    Bs[b_k + 2][b_n] = pb.z;
    Bs[b_k + 3][b_n] = pb.w;
    __syncthreads();
    if (t + 1 < ntile) { pa = ld_a((t + 1) * TK); pb = ld_b((t + 1) * TK); }
#pragma unroll
    for (int kk = 0; kk < TK; ++kk) {
      float4 a = *(const float4*)&As[kk][ty << 2];
      float4 b = *(const float4*)&Bs[kk][tx << 2];
      float av[4] = {a.x, a.y, a.z, a.w};
      float bv[4] = {b.x, b.y, b.z, b.w};
#pragma unroll
      for (int i = 0; i < 4; ++i)
#pragma unroll
        for (int j = 0; j < 4; ++j) acc[i][j] += av[i] * bv[j];
    }
  }

#pragma unroll
  for (int i = 0; i < 4; ++i) {
    int r = row0 + (ty << 2) + i;
    if (r >= M) continue;
#pragma unroll
    for (int j = 0; j < 4; ++j) {
      int c = col0 + (tx << 2) + j;
      if (c >= N) continue;
      float v = acc[i][j];
      if (ACT == 1) v = tanhf(v);
      if (ACT == 2) v = 1.0f / (1.0f + __expf(-v));
      C[(size_t)r * N + c] = v;
    }
  }
}

// Problem: N=10000, D1=20, D2=256, D3=128, NI=500
// Restructured (exact-math equivalent, 279 GF -> 83 GF):
//   g1   = adj @ z_igae          [N,20]
//   z1   = tanh(g1 @ w3)         [N,256]
//   t2   = z1 @ w4               [N,128]
//   z2   = tanh(adj @ t2)        [N,128]
//   g3   = adj @ z2              [N,128]
//   zhat = g3 @ w5               [N,500]   -> out0
//   Mm   = w5 @ w5^T             [128,128]
//   h    = g3 @ Mm               [N,128]
//   out1 = sigmoid(h @ g3^T)     [N,N]
extern "C" void kernel_launch(void* const* d_in, const int* in_sizes, int n_in,
                              void* d_out, int out_size, void* d_ws, size_t ws_size,
                              hipStream_t stream) {
  const float* z_igae = (const float*)d_in[0];
  const float* adj    = (const float*)d_in[1];
  const float* w3     = (const float*)d_in[2];
  const float* w4     = (const float*)d_in[3];
  const float* w5     = (const float*)d_in[4];

  const int N = 10000, D1 = 20, D2 = 256, D3 = 128, NI = 500;

  float* z_hat   = (float*)d_out;             // [N, NI]
  float* out_adj = (float*)d_out + (size_t)N * NI;  // [N, N]

  // workspace regions (write-before-read everywhere; 0xAA poison is fine)
  char* ws = (char*)d_ws;
  float* R1 = (float*)(ws);               // 10,240,000 B: z1 / z2 / h
  float* R2 = (float*)(ws + 10240000);    //  5,120,000 B: g1 / t2 / g3
  float* Mm = (float*)(ws + 15360000);    //     65,536 B: w5 @ w5^T

  dim3 blk(256);
  const int MT = (N + TM - 1) / TM;  // 157

  // g1 = adj @ z_igae  -> R2
  gemm_nn_f32<0><<<dim3(1, MT), blk, 0, stream>>>(adj, z_igae, R2, N, D1, N);
  // z1 = tanh(g1 @ w3) -> R1
  gemm_nn_f32<1><<<dim3(4, MT), blk, 0, stream>>>(R2, w3, R1, N, D2, D1);
  // t2 = z1 @ w4 -> R2
  gemm_nn_f32<0><<<dim3(2, MT), blk, 0, stream>>>(R1, w4, R2, N, D3, D2);
  // z2 = tanh(adj @ t2) -> R1
  gemm_nn_f32<1><<<dim3(2, MT), blk, 0, stream>>>(adj, R2, R1, N, D3, N);
  // g3 = adj @ z2 -> R2
  gemm_nn_f32<0><<<dim3(2, MT), blk, 0, stream>>>(adj, R1, R2, N, D3, N);
  // z_hat = g3 @ w5 -> out0
  gemm_nn_f32<0><<<dim3(8, MT), blk, 0, stream>>>(R2, w5, z_hat, N, NI, D3);
  // Mm = w5 @ w5^T
  gemm_nt_f32<0><<<dim3(2, 2), blk, 0, stream>>>(w5, w5, Mm, D3, D3, NI);
  // h = g3 @ Mm -> R1
  gemm_nn_f32<0><<<dim3(2, MT), blk, 0, stream>>>(R2, Mm, R1, N, D3, D3);
  // out1 = sigmoid(h @ g3^T)
  gemm_nt_f32<2><<<dim3(MT, MT), blk, 0, stream>>>(R1, R2, out_adj, N, N, D3);
}

// Round 2
// 1022.189 us; speedup vs baseline: 2.5650x; 2.5650x over previous
//
#include <hip/hip_runtime.h>
#include <cstddef>
#include <cstdint>

// R2: bf16-MFMA for the three adj GEMMs (split-K S=8) + bf16 recon GEMM.
// adj converted once to zero-padded bf16 [10048][10048] stored in the
// out_adj region of d_out (free scratch until the final recon write).
//
// Math (exact-equivalent restructure of reference, 279 GF -> ~83 GF):
//   g1   = adj @ z_igae          [N,20]
//   z1   = tanh(g1 @ w3)         [N,256]
//   t2   = z1 @ w4               [N,128]
//   z2   = tanh(adj @ t2)        [N,128]
//   g3   = adj @ z2              [N,128]
//   zhat = g3 @ w5               [N,500]             -> out0
//   Mm   = w5 @ w5^T             [128,128]
//   h    = g3 @ Mm               [N,128]
//   out1 = sigmoid(h @ g3^T)     [N,N]               -> out1

typedef __attribute__((ext_vector_type(8))) short bf16x8;
typedef __attribute__((ext_vector_type(4))) float f32x4;

__device__ inline unsigned short f2bf(float f) {
  union { float f; unsigned int u; } a; a.f = f;
  unsigned int u = a.u;
  u += 0x7fffu + ((u >> 16) & 1u);  // round-to-nearest-even
  return (unsigned short)(u >> 16);
}

__device__ inline void gl_lds16(const void* g, void* l) {
  __builtin_amdgcn_global_load_lds(
      (const __attribute__((address_space(1))) void*)g,
      (__attribute__((address_space(3))) void*)l, 16, 0, 0);
}

// ---------------------------------------------------------------------------
// bf16 MFMA GEMM:  C(+split) = act(A[M'x K'] @ Bt[N' x K']^T)
// A row-major stride lda, Bt row-major stride ldb (the "B^T" operand layout).
// Tile 64(M) x NT, BK=64, 256 threads = 4 waves, 16x16x32 MFMA.
// ACT: 0 = none (no output mask, padded partial buffer), 2 = sigmoid (masked).
// ---------------------------------------------------------------------------
template <int NT, int ACT>
__global__ __launch_bounds__(256)
void gemm_bf16(const short* __restrict__ A, int lda,
               const short* __restrict__ Bt, int ldb,
               float* __restrict__ C, long long cSplitStride, int ldc,
               int M, int Nvalid, int kChunks, int S) {
  __shared__ short As[64 * 64];        // [row][k], row = 128 B
  __shared__ short Bs[NT * 64];
  const int tid  = threadIdx.x;
  const int wave = tid >> 6;
  const int lane = tid & 63;
  const int row0 = blockIdx.y * 64;
  const int col0 = blockIdx.x * NT;
  const int s    = blockIdx.z;
  const int t0 = (int)((long long)s * kChunks / S);
  const int t1 = (int)((long long)(s + 1) * kChunks / S);

  f32x4 acc[NT / 16];
#pragma unroll
  for (int i = 0; i < NT / 16; ++i) acc[i] = (f32x4){0.f, 0.f, 0.f, 0.f};

  const int lr = lane >> 3;        // row within 8-row LDS chunk
  const int lk = (lane & 7) * 8;   // k element offset (16 B granule)

  for (int t = t0; t < t1; ++t) {
    const int k0 = t * 64;
    __syncthreads();
    // stage A: 8 KB = 8 chunks of 1024 B (64 lanes x 16 B), 2 per wave
#pragma unroll
    for (int i = 0; i < 2; ++i) {
      int c = wave + 4 * i;
      gl_lds16(A + (size_t)(row0 + 8 * c + lr) * lda + k0 + lk,
               (void*)(As + c * 512));
    }
    // stage Bt: NT*128 B = NT/8 chunks, NT/32 per wave
#pragma unroll
    for (int i = 0; i < NT / 32; ++i) {
      int c = wave + 4 * i;
      gl_lds16(Bt + (size_t)(col0 + 8 * c + lr) * ldb + k0 + lk,
               (void*)(Bs + c * 512));
    }
    __syncthreads();
#pragma unroll
    for (int ks = 0; ks < 2; ++ks) {
      bf16x8 af = *(const bf16x8*)&As[(wave * 16 + (lane & 15)) * 64 +
                                      ks * 32 + (lane >> 4) * 8];
#pragma unroll
      for (int nt = 0; nt < NT / 16; ++nt) {
        bf16x8 bfr = *(const bf16x8*)&Bs[(nt * 16 + (lane & 15)) * 64 +
                                         ks * 32 + (lane >> 4) * 8];
        acc[nt] = __builtin_amdgcn_mfma_f32_16x16x32_bf16(af, bfr, acc[nt], 0, 0, 0);
      }
    }
  }

  float* Cs = C + (long long)s * cSplitStride;
  const int rbase = row0 + wave * 16 + (lane >> 4) * 4;
  const int cbase = col0 + (lane & 15);
#pragma unroll
  for (int nt = 0; nt < NT / 16; ++nt) {
    const int cc = cbase + nt * 16;
#pragma unroll
    for (int r = 0; r < 4; ++r) {
      const int rr = rbase + r;
      float v = acc[nt][r];
      if (ACT == 2) {
        v = 1.0f / (1.0f + __expf(-v));
        if (rr < M && cc < Nvalid) Cs[(size_t)rr * ldc + cc] = v;
      } else {
        Cs[(size_t)rr * ldc + cc] = v;   // padded partial buffer, no mask
      }
    }
  }
}

// ---------------------------------------------------------------------------
// f32 tiled GEMMs for the small (K<=256) ops. 64x64 tile, 4x4/thread.
// ---------------------------------------------------------------------------
#define TK 16
#define TM 64
#define TN 64

template <int ACT, bool OBF16>
__global__ __launch_bounds__(256)
void gemm_nn_f32(const float* __restrict__ A, int lda,
                 const float* __restrict__ B, int ldb,
                 void* __restrict__ Cp, int ldc, int M, int N, int K) {
  __shared__ float Asm[TK][TM + 4];
  __shared__ float Bsm[TK][TN + 4];
  const int tid = threadIdx.x;
  const int tx = tid & 15, ty = tid >> 4;
  const int row0 = blockIdx.y * TM, col0 = blockIdx.x * TN;
  const int a_m = tid >> 2, a_k = (tid & 3) << 2;
  const int b_k = tid >> 4, b_n = (tid & 15) << 2;
  float acc[4][4] = {};
  const int ntile = (K + TK - 1) / TK;

  auto ld_a = [&](int k0) {
    float4 v = make_float4(0.f, 0.f, 0.f, 0.f);
    int r = row0 + a_m, k = k0 + a_k;
    if (r < M && k + 3 < K + (K & 3 ? 0 : 0) && k + 3 < K)
      v = *(const float4*)(A + (size_t)r * lda + k);
    else if (r < M && k < K)  // partial tail (lda-padded rows are safe)
      v = *(const float4*)(A + (size_t)r * lda + k);
    return v;
  };
  auto ld_b = [&](int k0) {
    float4 v = make_float4(0.f, 0.f, 0.f, 0.f);
    int k = k0 + b_k, c = col0 + b_n;
    if (k < K && c + 3 < N) v = *(const float4*)(B + (size_t)k * ldb + c);
    return v;
  };

  float4 pa = ld_a(0), pb = ld_b(0);
  for (int t = 0; t < ntile; ++t) {
    __syncthreads();
    Asm[a_k + 0][a_m] = pa.x; Asm[a_k + 1][a_m] = pa.y;
    Asm[a_k + 2][a_m] = pa.z; Asm[a_k + 3][a_m] = pa.w;
    *(float4*)&Bsm[b_k][b_n] = pb;
    __syncthreads();
    if (t + 1 < ntile) { pa = ld_a((t + 1) * TK); pb = ld_b((t + 1) * TK); }
    // mask K-tail contributions: elements with k>=K were loaded as part of a
    // float4 whose base k<K (rows are lda-padded) — zero them via Bsm mask:
    // ld_b already zeroes k>=K rows, so products with garbage A are zero. safe.
#pragma unroll
    for (int kk = 0; kk < TK; ++kk) {
      float4 a = *(const float4*)&Asm[kk][ty << 2];
      float4 b = *(const float4*)&Bsm[kk][tx << 2];
      float av[4] = {a.x, a.y, a.z, a.w};
      float bv[4] = {b.x, b.y, b.z, b.w};
#pragma unroll
      for (int i = 0; i < 4; ++i)
#pragma unroll
        for (int j = 0; j < 4; ++j) acc[i][j] += av[i] * bv[j];
    }
  }
#pragma unroll
  for (int i = 0; i < 4; ++i) {
    int r = row0 + (ty << 2) + i;
    if (r >= M) continue;
#pragma unroll
    for (int j = 0; j < 4; ++j) {
      int c = col0 + (tx << 2) + j;
      if (c >= N) continue;
      float v = acc[i][j];
      if (ACT == 1) v = tanhf(v);
      if (OBF16) ((unsigned short*)Cp)[(size_t)r * ldc + c] = f2bf(v);
      else       ((float*)Cp)[(size_t)r * ldc + c] = v;
    }
  }
}

template <int ACT>
__global__ __launch_bounds__(256)
void gemm_nt_f32(const float* __restrict__ A, int lda,
                 const float* __restrict__ B, int ldb,
                 float* __restrict__ C, int ldc, int M, int N, int K) {
  __shared__ float Asm[TK][TM + 4];
  __shared__ float Bsm[TK][TN + 4];
  const int tid = threadIdx.x;
  const int tx = tid & 15, ty = tid >> 4;
  const int row0 = blockIdx.y * TM, col0 = blockIdx.x * TN;
  const int a_m = tid >> 2, a_k = (tid & 3) << 2;
  const int b_n = tid >> 2, b_k = (tid & 3) << 2;
  float acc[4][4] = {};
  const int ntile = (K + TK - 1) / TK;

  auto ld_a = [&](int k0) {
    float4 v = make_float4(0.f, 0.f, 0.f, 0.f);
    int r = row0 + a_m, k = k0 + a_k;
    if (r < M && k + 3 < K) v = *(const float4*)(A + (size_t)r * lda + k);
    return v;
  };
  auto ld_b = [&](int k0) {
    float4 v = make_float4(0.f, 0.f, 0.f, 0.f);
    int c = col0 + b_n, k = k0 + b_k;
    if (c < N && k + 3 < K) v = *(const float4*)(B + (size_t)c * ldb + k);
    return v;
  };

  float4 pa = ld_a(0), pb = ld_b(0);
  for (int t = 0; t < ntile; ++t) {
    __syncthreads();
    Asm[a_k + 0][a_m] = pa.x; Asm[a_k + 1][a_m] = pa.y;
    Asm[a_k + 2][a_m] = pa.z; Asm[a_k + 3][a_m] = pa.w;
    Bsm[b_k + 0][b_n] = pb.x; Bsm[b_k + 1][b_n] = pb.y;
    Bsm[b_k + 2][b_n] = pb.z; Bsm[b_k + 3][b_n] = pb.w;
    __syncthreads();
    if (t + 1 < ntile) { pa = ld_a((t + 1) * TK); pb = ld_b((t + 1) * TK); }
#pragma unroll
    for (int kk = 0; kk < TK; ++kk) {
      float4 a = *(const float4*)&Asm[kk][ty << 2];
      float4 b = *(const float4*)&Bsm[kk][tx << 2];
      float av[4] = {a.x, a.y, a.z, a.w};
      float bv[4] = {b.x, b.y, b.z, b.w};
#pragma unroll
      for (int i = 0; i < 4; ++i)
#pragma unroll
        for (int j = 0; j < 4; ++j) acc[i][j] += av[i] * bv[j];
    }
  }
#pragma unroll
  for (int i = 0; i < 4; ++i) {
    int r = row0 + (ty << 2) + i;
    if (r >= M) continue;
#pragma unroll
    for (int j = 0; j < 4; ++j) {
      int c = col0 + (tx << 2) + j;
      if (c >= N) continue;
      C[(size_t)r * ldc + c] = acc[i][j];
    }
  }
}

// --------------------------- helper kernels --------------------------------
#define NROWS 10000
#define MP 10048   // padded to multiple of 64

__global__ void convert_adj(const float* __restrict__ adj, short* __restrict__ out) {
  int row = blockIdx.y;
  int c4 = (blockIdx.x * 256 + threadIdx.x) * 4;
  if (c4 >= MP) return;
  ushort4 o = {0, 0, 0, 0};
  if (row < NROWS && c4 < NROWS) {   // 10000 % 4 == 0
    float4 v = *(const float4*)(adj + (size_t)row * NROWS + c4);
    o.x = f2bf(v.x); o.y = f2bf(v.y); o.z = f2bf(v.z); o.w = f2bf(v.w);
  }
  *(ushort4*)(out + (size_t)row * MP + c4) = o;
}

__global__ void tr_zigae(const float* __restrict__ z, short* __restrict__ zt) {
  int m = blockIdx.x * 256 + threadIdx.x;  // up to 10240
  int n = blockIdx.y;                      // 32
  if (m >= MP) return;
  float v = (n < 20 && m < NROWS) ? z[(size_t)m * 20 + n] : 0.f;
  zt[(size_t)n * MP + m] = f2bf(v);
}

// [M][128] f32 -> [128][MP] bf16 (zero pad m>=M)
__global__ void transpose_c128(const float* __restrict__ in, int M,
                               short* __restrict__ out) {
  __shared__ float tile[32][33];
  int m0 = blockIdx.x * 32, n0 = blockIdx.y * 32;
  int tx = threadIdx.x, ty = threadIdx.y;  // 32 x 8
  for (int i = ty; i < 32; i += 8) {
    int m = m0 + i;
    tile[i][tx] = (m < M) ? in[(size_t)m * 128 + n0 + tx] : 0.f;
  }
  __syncthreads();
  for (int i = ty; i < 32; i += 8) {
    int n = n0 + i, m = m0 + tx;
    if (m < MP) out[(size_t)n * MP + m] = f2bf(tile[tx][i]);
  }
}

__global__ void reduce_g1(const float* __restrict__ P, float* __restrict__ g1) {
  int m = blockIdx.x * 4 + (threadIdx.x >> 5);
  int n = threadIdx.x & 31;
  if (m >= NROWS) return;
  float s = 0.f;
#pragma unroll
  for (int i = 0; i < 8; ++i) s += P[(size_t)i * MP * 32 + (size_t)m * 32 + n];
  g1[(size_t)m * 32 + n] = s;
}

template <int ACT>  // 1 = tanh
__global__ void reduce128(const float* __restrict__ P, float* __restrict__ outf,
                          short* __restrict__ outb, int M) {
  int m = blockIdx.x, n = threadIdx.x;
  if (m >= M) { if (outb) outb[(size_t)m * 128 + n] = 0; return; }
  float s = 0.f;
#pragma unroll
  for (int i = 0; i < 8; ++i) s += P[(size_t)i * MP * 128 + (size_t)m * 128 + n];
  if (ACT == 1) s = tanhf(s);
  if (outf) outf[(size_t)m * 128 + n] = s;
  if (outb) outb[(size_t)m * 128 + n] = f2bf(s);
}

__global__ void zero_bf16(short* p, int n) {
  int i = blockIdx.x * 256 + threadIdx.x;
  if (i < n) p[i] = 0;
}

// ---------------------------------------------------------------------------
extern "C" void kernel_launch(void* const* d_in, const int* in_sizes, int n_in,
                              void* d_out, int out_size, void* d_ws, size_t ws_size,
                              hipStream_t stream) {
  const float* z_igae = (const float*)d_in[0];
  const float* adj    = (const float*)d_in[1];
  const float* w3     = (const float*)d_in[2];
  const float* w4     = (const float*)d_in[3];
  const float* w5     = (const float*)d_in[4];

  const int M = NROWS, D2 = 256, D3 = 128, NI = 500;
  const int S = 8, KC = MP / 64;  // 157 BK-chunks

  float* z_hat   = (float*)d_out;                         // [M, NI]
  float* out_adj = (float*)d_out + (size_t)M * NI;        // [M, M] = 400 MB

  // scratch inside out_adj region (overwritten only by the final recon GEMM)
  char* oa = (char*)out_adj;
  short* adjb = (short*)oa;                               // [MP][MP] bf16, 202 MB
  float* P    = (float*)(oa + 204ll * 1024 * 1024);       // partials 8*MP*128*4 = 41 MB
  char*  sc   = oa + 248ll * 1024 * 1024;                 // scratch, ends < 290 MB
  float* z1   = (float*)(sc);                             // [M][256] 10.24 MB
  float* t2   = (float*)(sc + 11ll * 1024 * 1024);        // [M][128]  5.12 MB
  short* t2t  = (short*)(sc + 17ll * 1024 * 1024);        // [128][MP] 2.57 MB
  float* z2   = (float*)(sc + 20ll * 1024 * 1024);        // [M][128]  5.12 MB
  short* z2t  = (short*)(sc + 26ll * 1024 * 1024);        // [128][MP] 2.57 MB
  float* g1   = (float*)(sc + 29ll * 1024 * 1024);        // [M][32]   1.28 MB
  short* zt   = (short*)(sc + 31ll * 1024 * 1024);        // [32][MP]  0.64 MB
  float* Mm   = (float*)(sc + 32ll * 1024 * 1024);        // [128][128] 64 KB
  float* g3   = (float*)(sc + 33ll * 1024 * 1024);        // [M][128]  5.12 MB

  // recon inputs live in d_ws (must survive until recon writes out_adj)
  short* hb  = (short*)d_ws;                              // [MP][128]   2.57 MB
  short* g3b = (short*)d_ws + (size_t)MP * 128;           // [10112][128] 2.59 MB

  dim3 blk(256);
  const int MT = 157;

  // 1. adj -> bf16 padded
  convert_adj<<<dim3(10, MP), blk, 0, stream>>>(adj, adjb);
  // 2. z_igae^T -> bf16 [32][MP]
  tr_zigae<<<dim3(40, 32), blk, 0, stream>>>(z_igae, zt);
  // 3. g1 partials = adj @ z_igae (split-K)
  gemm_bf16<32, 0><<<dim3(1, MT, S), blk, 0, stream>>>(
      adjb, MP, zt, MP, P, (long long)MP * 32, 32, M, 32, KC, S);
  reduce_g1<<<dim3(2500), dim3(128), 0, stream>>>(P, g1);
  // 4. z1 = tanh(g1 @ w3)
  gemm_nn_f32<1, false><<<dim3(4, MT), blk, 0, stream>>>(g1, 32, w3, D2, z1, D2, M, D2, 20);
  // 5. t2 = z1 @ w4
  gemm_nn_f32<0, false><<<dim3(2, MT), blk, 0, stream>>>(z1, D2, w4, D3, t2, D3, M, D3, D2);
  transpose_c128<<<dim3(314, 4), dim3(32, 8), 0, stream>>>(t2, M, t2t);
  // 6. z2 = tanh(adj @ t2)
  gemm_bf16<128, 0><<<dim3(1, MT, S), blk, 0, stream>>>(
      adjb, MP, t2t, MP, P, (long long)MP * 128, 128, M, 128, KC, S);
  reduce128<1><<<dim3(M), dim3(128), 0, stream>>>(P, z2, (short*)nullptr, M);
  transpose_c128<<<dim3(314, 4), dim3(32, 8), 0, stream>>>(z2, M, z2t);
  // 7. g3 = adj @ z2  (f32 + bf16 copies; bf16 padded to 10112 rows)
  gemm_bf16<128, 0><<<dim3(1, MT, S), blk, 0, stream>>>(
      adjb, MP, z2t, MP, P, (long long)MP * 128, 128, M, 128, KC, S);
  reduce128<0><<<dim3(10112), dim3(128), 0, stream>>>(P, g3, g3b, M);
  // 8. z_hat = g3 @ w5 -> out0
  gemm_nn_f32<0, false><<<dim3(8, MT), blk, 0, stream>>>(g3, D3, w5, NI, z_hat, NI, M, NI, D3);
  // 9. Mm = w5 @ w5^T
  gemm_nt_f32<0><<<dim3(2, 2), blk, 0, stream>>>(w5, NI, w5, NI, Mm, D3, D3, D3, NI);
  // 10. h = g3 @ Mm (bf16 out) + zero pad rows 10000..10047
  gemm_nn_f32<0, true><<<dim3(2, MT), blk, 0, stream>>>(g3, D3, Mm, D3, (void*)hb, D3, M, D3, D3);
  zero_bf16<<<dim3(24), blk, 0, stream>>>(hb + (size_t)M * 128, 48 * 128);
  // 11. out1 = sigmoid(h @ g3^T)  — overwrites all scratch in out_adj
  gemm_bf16<128, 2><<<dim3(79, MT, 1), blk, 0, stream>>>(
      hb, 128, g3b, 128, out_adj, 0, M, M, M, 2, 1);
}